// Round 3
// baseline (279.521 us; speedup 1.0000x reference)
//
#include <hip/hip_runtime.h>

// Shapes (fixed by setup_inputs): N=1, L1=256, K=128, L2=1024,
// c_s=384, c_m=256, ch=32, c_z=128
#define L1V 256
#define L2V 1024
#define KV  128
#define CSV 384
#define CMV 256
#define CHV 32
#define CZV 128

// Native vector types for __builtin_nontemporal_* (HIP float4/float2 are
// classes, which the builtin rejects).
typedef float f4v __attribute__((ext_vector_type(4)));
typedef float f2v __attribute__((ext_vector_type(2)));

__device__ __forceinline__ float4 f4zero() { return make_float4(0.f,0.f,0.f,0.f); }

__device__ __forceinline__ float4 nt_load4(const float4* p) {
  f4v t = __builtin_nontemporal_load((const f4v*)p);
  return make_float4(t.x, t.y, t.z, t.w);
}

// Per-row LN stats (full-wave reduction over 256 elems = 64 lanes x float4),
// then accumulate normalized row into xs.
__device__ __forceinline__ void ln_accum(const float4 x, float4& xs) {
  float s1 = x.x + x.y + x.z + x.w;
  float s2 = fmaf(x.x, x.x, fmaf(x.y, x.y, fmaf(x.z, x.z, x.w * x.w)));
  #pragma unroll
  for (int off = 32; off > 0; off >>= 1) {
    s1 += __shfl_xor(s1, off, 64);
    s2 += __shfl_xor(s2, off, 64);
  }
  const float mu   = s1 * (1.0f / CMV);
  const float rstd = rsqrtf(s2 * (1.0f / CMV) - mu * mu + 1e-5f);
  xs.x = fmaf(x.x - mu, rstd, xs.x);
  xs.y = fmaf(x.y - mu, rstd, xs.y);
  xs.z = fmaf(x.z - mu, rstd, xs.z);
  xs.w = fmaf(x.w - mu, rstd, xs.w);
}

// ---------------------------------------------------------------------------
// R4 FRONT KERNEL (heterogeneous, 1 launch instead of 3):
//   blocks    0..1023 : msum path (unchanged R2 logic) — HBM-bound, ~134 MB
//   blocks 1024..1279 : fused a+t path — a-rows recomputed per t-block (16x
//                       redundant LN+proj, trivially cheap) so there is no
//                       a->t dependency; this VALU/L2 work rides for free
//                       under the msum HBM stream (all 1280 blocks
//                       co-resident: 20 KB LDS, 256 thr -> 8 blocks/CU cap).
// ---------------------------------------------------------------------------
__global__ __launch_bounds__(256) void front_kernel(
    // msum path args
    const float* __restrict__ m,  const float* __restrict__ gm,
    const float* __restrict__ bm, const float* __restrict__ Wg,
    const float* __restrict__ bg, float* __restrict__ msum,
    // a+t path args
    const float* __restrict__ s,  const float* __restrict__ gs,
    const float* __restrict__ bs, const float* __restrict__ Wa,
    const float* __restrict__ ba, const float* __restrict__ Wout,
    float* __restrict__ T)
{
  const int tid  = threadIdx.x;
  const int wave = tid >> 6;
  const int lane = tid & 63;

  if (blockIdx.x < 1024) {
    // ---------------- msum path (verbatim R2) ----------------
    const int j = blockIdx.x;
    const float4* base = (const float4*)m;  // row k at float4 idx (k*1024+j)*64

    float4 xs = f4zero();
    float4 x0 = nt_load4(&base[(((size_t)wave << 10) + j) * 64 + lane]);
    float4 x1 = nt_load4(&base[(((size_t)(wave + 4) << 10) + j) * 64 + lane]);

    for (int k = wave; k < KV; k += 8) {
      float4 n0 = f4zero(), n1 = f4zero();
      if (k + 8  < KV) n0 = nt_load4(&base[(((size_t)(k + 8)  << 10) + j) * 64 + lane]);
      if (k + 12 < KV) n1 = nt_load4(&base[(((size_t)(k + 12) << 10) + j) * 64 + lane]);
      ln_accum(x0, xs);
      ln_accum(x1, xs);
      x0 = n0; x1 = n1;
    }

    __shared__ float xsum[4][CMV];
    ((float4*)xsum[wave])[lane] = xs;
    __syncthreads();

    __shared__ float y[CMV];
    y[tid] = (xsum[0][tid] + xsum[1][tid] + xsum[2][tid] + xsum[3][tid]) * gm[tid]
             + (float)KV * bm[tid];
    __syncthreads();

    const int c     = tid & 31;
    const int chunk = tid >> 5;
    float p = 0.f;
    #pragma unroll
    for (int q = 0; q < 32; ++q) {
      const int e = (chunk << 5) + q;
      p = fmaf(y[e], Wg[(e << 5) + c], p);
    }
    __shared__ float pr[256];
    pr[tid] = p;
    __syncthreads();
    if (tid < 32) {
      float acc = 0.f;
      #pragma unroll
      for (int r = 0; r < 8; ++r) acc += pr[tid + (r << 5)];
      msum[(j << 5) + tid] = acc + (float)KV * bg[tid];
    }
  } else {
    // ---------------- fused a + t path ----------------
    const int b   = blockIdx.x - 1024;   // 0..255
    const int bx  = b & 15;              // idx chunk (z*e subrange)
    const int i0  = (b >> 4) << 4;       // 16 a-rows: i0..i0+15
    const int idx = (bx << 8) + tid;     // 0..4095

    __shared__ float ylds[8][CSV];       // 12 KB (double-pass over 16 rows)
    __shared__ float as_[16 * CHV];      // 2 KB

    #pragma unroll
    for (int halfp = 0; halfp < 2; ++halfp) {
      // each wave computes LN(y) for 2 of the 8 rows in this half
      #pragma unroll
      for (int rr = 0; rr < 2; ++rr) {
        const int r = (wave << 1) + rr;          // 0..7
        const int i = i0 + (halfp << 3) + r;
        float xv[6];
        #pragma unroll
        for (int q = 0; q < 6; ++q) xv[q] = s[i * CSV + (q << 6) + lane];
        float s1 = 0.f, s2 = 0.f;
        #pragma unroll
        for (int q = 0; q < 6; ++q) { s1 += xv[q]; s2 = fmaf(xv[q], xv[q], s2); }
        #pragma unroll
        for (int off = 32; off > 0; off >>= 1) {
          s1 += __shfl_xor(s1, off, 64);
          s2 += __shfl_xor(s2, off, 64);
        }
        const float mu   = s1 * (1.0f / CSV);
        const float rstd = rsqrtf(s2 * (1.0f / CSV) - mu * mu + 1e-5f);
        #pragma unroll
        for (int q = 0; q < 6; ++q) {
          const int e = (q << 6) + lane;
          ylds[r][e] = (xv[q] - mu) * rstd * gs[e] + bs[e];
        }
      }
      __syncthreads();
      // proj: 8 rows x 32 c = 256 outputs, one per thread
      {
        const int ii = tid >> 5;   // 0..7
        const int c  = tid & 31;
        float acc = ba[c];
        #pragma unroll 8
        for (int e = 0; e < CSV; ++e)
          acc = fmaf(ylds[ii][e], Wa[(e << 5) + c], acc);
        as_[(((halfp << 3) + ii) << 5) + c] = acc;
      }
      __syncthreads();  // protects ylds reuse (halfp=1) and as_ completion
    }

    // t-projection: T[i0+ii, idx] = sum_c as_[ii,c] * Wout[c*4096 + idx]
    float w[32];
    #pragma unroll
    for (int c = 0; c < 32; ++c) w[c] = Wout[(c << 12) + idx];

    #pragma unroll 4
    for (int ii = 0; ii < 16; ++ii) {
      float acc = 0.f;
      #pragma unroll
      for (int c = 0; c < 32; ++c)
        acc = fmaf(as_[(ii << 5) + c], w[c], acc);
      T[((size_t)(i0 + ii) << 12) + idx] = acc;
    }
  }
}

// ---------------------------------------------------------------------------
// Kernel C: out[i,j,z] = (m_sum[j,:] @ T[i][:,z] + b_out[z]) / norm
// R4: grid (2,256) -> (4,256): 64 j per wave, ~3 waves/SIMD (VGPR ~150)
// instead of 2 — better hiding of the uniform msum L2 loads under the NT
// store stream. Extra T re-reads: +48 MB L2 (~1.4 us aggregate), noise.
// j wave-uniform; T in 64 VGPRs (float2/lane, inv_norm pre-folded);
// zero LDS, zero barriers; NT float2 stores.
// ---------------------------------------------------------------------------
__global__ __launch_bounds__(256) void out_kernel(
    const float* __restrict__ msum, const float* __restrict__ T,
    const float* __restrict__ bout, float* __restrict__ out)
{
  const int quart = blockIdx.x;  // 0..3 (j quarters)
  const int i     = blockIdx.y;  // 0..255
  const int wid   = __builtin_amdgcn_readfirstlane((int)(threadIdx.x >> 6)); // 0..3
  const int lane  = threadIdx.x & 63;
  const int z0    = lane << 1;   // z pair start: 0,2,...,126

  const float inv_norm = 1.0f / ((float)KV + 1e-3f);

  // T[i, e, z0:z0+2] for all 32 e, pre-scaled by inv_norm (folds the /norm)
  float2 Tr[32];
  #pragma unroll
  for (int e = 0; e < 32; ++e) {
    const float2 t = *(const float2*)(T + ((size_t)i << 12) + (e << 7) + z0);
    Tr[e] = make_float2(t.x * inv_norm, t.y * inv_norm);
  }
  float2 bz = *(const float2*)(bout + z0);
  bz.x *= inv_norm; bz.y *= inv_norm;

  const int j0 = (quart << 8) + (wid << 6);   // wave's j base; 64 consecutive j
  float* const outp = out + ((size_t)i << 17);

  float4 mA[8], mB[8];

#define LOADROW(BUF, J) do {                                                \
    const float4* mr = (const float4*)(msum + ((size_t)(J) << 5));          \
    _Pragma("unroll")                                                       \
    for (int q = 0; q < 8; ++q) BUF[q] = mr[q];                             \
  } while (0)

#define FMA_STORE(BUF, J) do {                                              \
    float ax = bz.x, ay = bz.y;                                             \
    _Pragma("unroll")                                                       \
    for (int q = 0; q < 8; ++q) {                                           \
      const float4 mq = BUF[q];                                             \
      ax = fmaf(mq.x, Tr[(q<<2)+0].x, ax); ay = fmaf(mq.x, Tr[(q<<2)+0].y, ay); \
      ax = fmaf(mq.y, Tr[(q<<2)+1].x, ax); ay = fmaf(mq.y, Tr[(q<<2)+1].y, ay); \
      ax = fmaf(mq.z, Tr[(q<<2)+2].x, ax); ay = fmaf(mq.z, Tr[(q<<2)+2].y, ay); \
      ax = fmaf(mq.w, Tr[(q<<2)+3].x, ax); ay = fmaf(mq.w, Tr[(q<<2)+3].y, ay); \
    }                                                                       \
    f2v ov; ov.x = ax; ov.y = ay;                                           \
    __builtin_nontemporal_store(ov,                                         \
        (f2v*)(outp + ((size_t)(J) << 7) + z0));                            \
  } while (0)

  LOADROW(mA, j0);
  for (int jj = 0; jj < 64; jj += 2) {
    LOADROW(mB, j0 + jj + 1);
    FMA_STORE(mA, j0 + jj);
    if (jj + 2 < 64) LOADROW(mA, j0 + jj + 2);
    FMA_STORE(mB, j0 + jj + 1);
  }
#undef LOADROW
#undef FMA_STORE
}

// ---------------------------------------------------------------------------
extern "C" void kernel_launch(void* const* d_in, const int* in_sizes, int n_in,
                              void* d_out, int out_size, void* d_ws, size_t ws_size,
                              hipStream_t stream) {
  (void)in_sizes; (void)n_in; (void)out_size; (void)ws_size;
  const float* s    = (const float*)d_in[0];
  const float* m    = (const float*)d_in[1];
  const float* g_ab = (const float*)d_in[2];
  const float* b_ab = (const float*)d_in[3];
  const float* g_ag = (const float*)d_in[4];
  const float* b_ag = (const float*)d_in[5];
  const float* Wab  = (const float*)d_in[6];
  const float* bab  = (const float*)d_in[7];
  const float* Wag  = (const float*)d_in[8];
  const float* bag  = (const float*)d_in[9];
  const float* Wout = (const float*)d_in[10];
  const float* bout = (const float*)d_in[11];
  float* out = (float*)d_out;

  // workspace layout (fp32): msum[1024*32] | (unused a slot) | T[256*32*128]
  float* msum = (float*)d_ws;
  float* T    = msum + 32768 + 8192;   // 4 MB

  hipLaunchKernelGGL(front_kernel, dim3(1280), dim3(256), 0, stream,
                     m, g_ag, b_ag, Wag, bag, msum,
                     s, g_ab, b_ab, Wab, bab, Wout, T);
  hipLaunchKernelGGL(out_kernel, dim3(4, 256), dim3(256), 0, stream,
                     msum, T, bout, out);
}